// Round 19
// baseline (68.747 us; speedup 1.0000x reference)
//
#include <hip/hip_runtime.h>

// Problem dims (fixed by reference)
#define BB   2
#define NBB  32
#define PP   128
#define FF   32
#define HH   32
#define NO   8
#define OUTC 32
#define NROWS (BB*NBB*PP)   // 8192

typedef float    f32x4 __attribute__((ext_vector_type(4)));
typedef _Float16 f16x8 __attribute__((ext_vector_type(8)));
typedef _Float16 f16x4 __attribute__((ext_vector_type(4)));
typedef _Float16 f16x2 __attribute__((ext_vector_type(2)));

__device__ __forceinline__ float elu_f(float x){
    return x > 0.0f ? x : (__expf(x) - 1.0f);
}
// packed fp32x2 -> fp16x2 (RTZ), bit-cast to _Float16 vector type
__device__ __forceinline__ f16x2 pk16(float a, float b){
    return __builtin_bit_cast(f16x2, __builtin_amdgcn_cvt_pkrtz(a, b));
}

// Kernel A: node MLP + projection to pa/pb (pair_b0 folded into pa).
__global__ __launch_bounds__(256) void node_kernel(
    const float* __restrict__ x,  const float* __restrict__ msk,
    const float* __restrict__ w0, const float* __restrict__ b0,
    const float* __restrict__ w1, const float* __restrict__ b1,
    const float* __restrict__ w2, const float* __restrict__ b2,
    const float* __restrict__ pw0,const float* __restrict__ pb0,
    float* __restrict__ pa, float* __restrict__ pb)
{
    int row = blockIdx.x*256 + threadIdx.x;
    if (row >= NROWS) return;

    float xr[FF];
    const float4* xp = reinterpret_cast<const float4*>(x + (size_t)row*FF);
#pragma unroll
    for (int q=0;q<FF/4;q++){ float4 v=xp[q]; xr[4*q]=v.x; xr[4*q+1]=v.y; xr[4*q+2]=v.z; xr[4*q+3]=v.w; }

    float h[HH];
#pragma unroll
    for (int k=0;k<HH;k++) h[k]=b0[k];
#pragma unroll
    for (int m=0;m<FF;m++){
        float xm = xr[m];
#pragma unroll
        for (int k=0;k<HH;k++) h[k] += xm * w0[m*HH+k];
    }
#pragma unroll
    for (int k=0;k<HH;k++) h[k]=elu_f(h[k]);

    float g[HH];
#pragma unroll
    for (int k=0;k<HH;k++) g[k]=b1[k];
#pragma unroll
    for (int m=0;m<HH;m++){
        float hm=h[m];
#pragma unroll
        for (int k=0;k<HH;k++) g[k] += hm * w1[m*HH+k];
    }
#pragma unroll
    for (int k=0;k<HH;k++) g[k]=elu_f(g[k]);

    float mk = msk[row];
    float npj[NO];
#pragma unroll
    for (int k=0;k<NO;k++) npj[k]=b2[k];
#pragma unroll
    for (int m=0;m<HH;m++){
        float gm=g[m];
#pragma unroll
        for (int k=0;k<NO;k++) npj[k] += gm * w2[m*NO+k];
    }
#pragma unroll
    for (int k=0;k<NO;k++) npj[k]=elu_f(npj[k])*mk;

    float pav[HH], pbv[HH];
#pragma unroll
    for (int k=0;k<HH;k++){ pav[k]=pb0[k]; pbv[k]=0.0f; }
#pragma unroll
    for (int m=0;m<NO;m++){
        float nm=npj[m];
#pragma unroll
        for (int k=0;k<HH;k++){
            pav[k] += nm * pw0[m*HH+k];
            pbv[k] += nm * pw0[(NO+m)*HH+k];
        }
    }
    float4* pap = reinterpret_cast<float4*>(pa + (size_t)row*HH);
    float4* pbp = reinterpret_cast<float4*>(pb + (size_t)row*HH);
#pragma unroll
    for (int q=0;q<HH/4;q++){
        pap[q]=make_float4(pav[4*q],pav[4*q+1],pav[4*q+2],pav[4*q+3]);
        pbp[q]=make_float4(pbv[4*q],pbv[4*q+1],pbv[4*q+2],pbv[4*q+3]);
    }
}

// ---- Transposed-MFMA pair kernel, fp16, DIRECT NT D-fragment stores ----
// R18 (WIN, 66->54 us) proved the floor was L2 dirty-line ALLOCATION on the
// store path: nontemporal full-line streams bypass it. R18->R19: drop the
// wave-local LDS transpose (2 ds_write + 2 ds_read + lgkm waits per i) --
// NT needs full 64 B SECTOR coverage, not full 128 B lines. The direct
// D-fragment store already spans 16 rows x contiguous 64 B per instruction
// (4 h-lanes x f32x4), mtO=0/1 halves of each 128 B line back-to-back.
// (R3's NT disaster was 16 B quarter-sector fragments; 64 B = full sector.)
//   A frag (16x16x32): row m=ln(+16mt), k=8h+{0..7}
//   B frag: col=pair j=64p+16w+ln, k=8h+{0..7}
//   D frag: col=pair j, feat 16mtO+4h+{0..3} -> NT f32x4 store
//   L1 D-frag == 16x16x16 B-frag (kc=mt chain) -> zero-LDS layer handoff.
#define SM_SIZE 1024     // pas: 8 rows * 32 f32

__global__ __launch_bounds__(256, 5) void pair_kernel(
    const float* __restrict__ pa, const float* __restrict__ pb,
    const float* __restrict__ pw1, const float* __restrict__ pb1,
    const float* __restrict__ pw2, const float* __restrict__ pb2,
    float* __restrict__ out)
{
    __shared__ __align__(16) float pas[SM_SIZE/4];

    const int t   = threadIdx.x;
    const int l   = t & 63;
    const int w   = t >> 6;
    const int h   = l >> 4;
    const int ln  = l & 15;
    const int bnb = blockIdx.x >> 5;
    const int ic  = (blockIdx.x >> 1) & 15;
    const int p   = blockIdx.x & 1;
    const int jme = 64*p + 16*w + ln;      // this lane's pair row j

    // ---- stage pa rows for this block's 8 i's (pair_b0 folded)
    if (t < 64)
        ((f32x4*)pas)[t] = ((const f32x4*)(pa + ((size_t)bnb*PP + ic*8)*HH))[t];

    // ---- Layer-1 W1^T A-fragments (16x16x32: k=8h+{0..7})
    f16x8 wfr1[2];   // [mt]
#pragma unroll
    for (int mt=0; mt<2; mt++){
        f16x8 a;
#pragma unroll
        for (int e=0; e<8; e++)
            a[e] = (_Float16)pw1[(8*h+e)*32 + 16*mt + ln];   // W1^T[m][k]=W1[k][m]
        wfr1[mt] = a;
    }
    // ---- Layer-2 W2^T A-fragments (16x16x16: k=4h+{0..3}, chained kc)
    f16x4 w2t[2][2]; // [mtO][kc]
#pragma unroll
    for (int mtO=0; mtO<2; mtO++)
#pragma unroll
    for (int kc=0; kc<2; kc++){
        f16x4 a;
#pragma unroll
        for (int e=0; e<4; e++)
            a[e] = (_Float16)pw2[(16*kc + 4*h + e)*32 + 16*mtO + ln];
        w2t[mtO][kc] = a;
    }

    // ---- biases as D-fragment f32x4 (feature = 16mt+4h+q)
    f32x4 b1v[2], b2v[2];
#pragma unroll
    for (int mt=0; mt<2; mt++){
        b1v[mt] = *(const f32x4*)(pb1 + 16*mt + 4*h);
        b2v[mt] = *(const f32x4*)(pb2 + 16*mt + 4*h);
    }

    // ---- pb slice: this lane's B-frag k-slice for its single j
    float pbr[8];
    {
        const float* q = pb + ((size_t)bnb*PP + jme)*HH + 8*h;
        f32x4 v0 = *(const f32x4*)q, v1 = *(const f32x4*)(q+4);
#pragma unroll
        for (int c=0;c<4;c++){ pbr[c]=v0[c]; pbr[4+c]=v1[c]; }
    }
    __syncthreads();   // pas visible to all

    for (int i = 0; i < 8; i++){
        // ---- H0^T B-fragment straight into registers (fp16, packed cvt)
        float par[8];
        {
            const f32x4* pp = (const f32x4*)(pas + i*32 + 8*h);
            f32x4 v0 = pp[0], v1 = pp[1];
#pragma unroll
            for (int c=0;c<4;c++){ par[c]=v0[c]; par[4+c]=v1[c]; }
        }
        float e0[8];
#pragma unroll
        for (int e=0; e<8; e++) e0[e] = elu_f(par[e] + pbr[e]);
        f16x2 p0 = pk16(e0[0], e0[1]);
        f16x2 p1 = pk16(e0[2], e0[3]);
        f16x2 p2 = pk16(e0[4], e0[5]);
        f16x2 p3 = pk16(e0[6], e0[7]);
        f16x8 bh = {p0[0],p0[1],p1[0],p1[1],p2[0],p2[1],p3[0],p3[1]};

        // ---- Layer 1: H1^T = W1^T @ H0^T (K=32)
        f32x4 acc[2];   // [mt]
#pragma unroll
        for (int mt=0; mt<2; mt++)
            acc[mt] = __builtin_amdgcn_mfma_f32_16x16x32_f16(
                          wfr1[mt], bh, b1v[mt], 0,0,0);

        // ---- elu + cvt: acc IS the 16x16x16 B-fragment (kc = mt)
        f16x4 bf[2];    // [kc]
#pragma unroll
        for (int kc=0; kc<2; kc++){
            f16x2 q0 = pk16(elu_f(acc[kc][0]), elu_f(acc[kc][1]));
            f16x2 q1 = pk16(elu_f(acc[kc][2]), elu_f(acc[kc][3]));
            f16x4 pp = {q0[0],q0[1],q1[0],q1[1]};
            bf[kc] = pp;
        }

        // ---- Layer 2: O^T = W2^T @ H1^T (2 chained K=16 MFMAs) + NT store
        float* obase = out + ((size_t)(bnb*PP + ic*8 + i))*PP*OUTC;
#pragma unroll
        for (int mtO=0; mtO<2; mtO++){
            f32x4 c = b2v[mtO];
            c = __builtin_amdgcn_mfma_f32_16x16x16f16(w2t[mtO][0], bf[0], c, 0,0,0);
            c = __builtin_amdgcn_mfma_f32_16x16x16f16(w2t[mtO][1], bf[1], c, 0,0,0);
            f32x4 o;
#pragma unroll
            for (int q=0; q<4; q++) o[q] = elu_f(c[q]);
            __builtin_nontemporal_store(o,
                (f32x4*)(obase + (size_t)jme*OUTC + 16*mtO + 4*h));
        }
    }
}

extern "C" void kernel_launch(void* const* d_in, const int* in_sizes, int n_in,
                              void* d_out, int out_size, void* d_ws, size_t ws_size,
                              hipStream_t stream) {
    const float* x    = (const float*)d_in[0];
    const float* msk  = (const float*)d_in[1];
    const float* nw0  = (const float*)d_in[2];
    const float* nb0  = (const float*)d_in[3];
    const float* nw1  = (const float*)d_in[4];
    const float* nb1  = (const float*)d_in[5];
    const float* nw2  = (const float*)d_in[6];
    const float* nb2  = (const float*)d_in[7];
    const float* pw0  = (const float*)d_in[8];
    const float* pb0  = (const float*)d_in[9];
    const float* pw1  = (const float*)d_in[10];
    const float* pb1  = (const float*)d_in[11];
    const float* pw2  = (const float*)d_in[12];
    const float* pb2  = (const float*)d_in[13];
    float* out = (float*)d_out;

    float* pa = (float*)d_ws;                       // 8192*32 floats = 1 MiB
    float* pb = pa + (size_t)NROWS*HH;              // +1 MiB

    node_kernel<<<NROWS/256, 256, 0, stream>>>(x, msk, nw0, nb0, nw1, nb1,
                                               nw2, nb2, pw0, pb0, pa, pb);
    pair_kernel<<<BB*NBB*32, 256, 0, stream>>>(pa, pb, pw1, pb1,
                                               pw2, pb2, out);
}

// Round 20
// 53.791 us; speedup vs baseline: 1.2780x; 1.2780x over previous
//
#include <hip/hip_runtime.h>

// Problem dims (fixed by reference)
#define BB   2
#define NBB  32
#define PP   128
#define FF   32
#define HH   32
#define NO   8
#define OUTC 32
#define NROWS (BB*NBB*PP)   // 8192

typedef float    f32x4 __attribute__((ext_vector_type(4)));
typedef _Float16 f16x8 __attribute__((ext_vector_type(8)));
typedef _Float16 f16x4 __attribute__((ext_vector_type(4)));
typedef _Float16 f16x2 __attribute__((ext_vector_type(2)));

__device__ __forceinline__ float elu_f(float x){
    return x > 0.0f ? x : (__expf(x) - 1.0f);
}
// packed fp32x2 -> fp16x2 (RTZ), bit-cast to _Float16 vector type
__device__ __forceinline__ f16x2 pk16(float a, float b){
    return __builtin_bit_cast(f16x2, __builtin_amdgcn_cvt_pkrtz(a, b));
}

// Kernel A: node MLP + projection to pa/pb (pair_b0 folded into pa).
__global__ __launch_bounds__(256) void node_kernel(
    const float* __restrict__ x,  const float* __restrict__ msk,
    const float* __restrict__ w0, const float* __restrict__ b0,
    const float* __restrict__ w1, const float* __restrict__ b1,
    const float* __restrict__ w2, const float* __restrict__ b2,
    const float* __restrict__ pw0,const float* __restrict__ pb0,
    float* __restrict__ pa, float* __restrict__ pb)
{
    int row = blockIdx.x*256 + threadIdx.x;
    if (row >= NROWS) return;

    float xr[FF];
    const float4* xp = reinterpret_cast<const float4*>(x + (size_t)row*FF);
#pragma unroll
    for (int q=0;q<FF/4;q++){ float4 v=xp[q]; xr[4*q]=v.x; xr[4*q+1]=v.y; xr[4*q+2]=v.z; xr[4*q+3]=v.w; }

    float h[HH];
#pragma unroll
    for (int k=0;k<HH;k++) h[k]=b0[k];
#pragma unroll
    for (int m=0;m<FF;m++){
        float xm = xr[m];
#pragma unroll
        for (int k=0;k<HH;k++) h[k] += xm * w0[m*HH+k];
    }
#pragma unroll
    for (int k=0;k<HH;k++) h[k]=elu_f(h[k]);

    float g[HH];
#pragma unroll
    for (int k=0;k<HH;k++) g[k]=b1[k];
#pragma unroll
    for (int m=0;m<HH;m++){
        float hm=h[m];
#pragma unroll
        for (int k=0;k<HH;k++) g[k] += hm * w1[m*HH+k];
    }
#pragma unroll
    for (int k=0;k<HH;k++) g[k]=elu_f(g[k]);

    float mk = msk[row];
    float npj[NO];
#pragma unroll
    for (int k=0;k<NO;k++) npj[k]=b2[k];
#pragma unroll
    for (int m=0;m<HH;m++){
        float gm=g[m];
#pragma unroll
        for (int k=0;k<NO;k++) npj[k] += gm * w2[m*NO+k];
    }
#pragma unroll
    for (int k=0;k<NO;k++) npj[k]=elu_f(npj[k])*mk;

    float pav[HH], pbv[HH];
#pragma unroll
    for (int k=0;k<HH;k++){ pav[k]=pb0[k]; pbv[k]=0.0f; }
#pragma unroll
    for (int m=0;m<NO;m++){
        float nm=npj[m];
#pragma unroll
        for (int k=0;k<HH;k++){
            pav[k] += nm * pw0[m*HH+k];
            pbv[k] += nm * pw0[(NO+m)*HH+k];
        }
    }
    float4* pap = reinterpret_cast<float4*>(pa + (size_t)row*HH);
    float4* pbp = reinterpret_cast<float4*>(pb + (size_t)row*HH);
#pragma unroll
    for (int q=0;q<HH/4;q++){
        pap[q]=make_float4(pav[4*q],pav[4*q+1],pav[4*q+2],pav[4*q+3]);
        pbp[q]=make_float4(pbv[4*q],pbv[4*q+1],pbv[4*q+2],pbv[4*q+3]);
    }
}

// ---- Transposed-MFMA pair kernel, fp16, NT full-line streaming stores ----
// EXACT REVERT to R18 (54.1 us, best known). R19 falsified the 64 B-NT
// variant (68.7 us): NT needs BOTH the bypass policy AND >=full-line
// contiguity per instruction -- separate 64 B NT halves RMW at the memory
// controller (no L2 merge point). The wave-local LDS transpose (~2 us) buys
// the 1 KB contiguous spans that make NT stream cleanly (worth ~12 us).
//   A frag (16x16x32): row m=ln(+16mt), k=8h+{0..7}
//   B frag: col=pair j, k=8h+{0..7};  D frag: col=pair j, feat 16mt+4h+{0..3}
//   L1 D-frag == 16x16x16 B-frag (kc=mt chain) -> zero-LDS layer handoff.
// Wave-local 2 KB LDS transpose tile (XOR-swizzled, no barriers).
#define SM_SIZE (1024 + 4*2048)   // pas + 4 wave tiles

__global__ __launch_bounds__(256, 5) void pair_kernel(
    const float* __restrict__ pa, const float* __restrict__ pb,
    const float* __restrict__ pw1, const float* __restrict__ pb1,
    const float* __restrict__ pw2, const float* __restrict__ pb2,
    float* __restrict__ out)
{
    __shared__ __align__(16) char smem[SM_SIZE];
    float* pas = (float*)smem;

    const int t   = threadIdx.x;
    const int l   = t & 63;
    const int w   = t >> 6;
    const int h   = l >> 4;
    const int ln  = l & 15;
    const int bnb = blockIdx.x >> 5;
    const int ic  = (blockIdx.x >> 1) & 15;
    const int p   = blockIdx.x & 1;
    const int jme = 64*p + 16*w + ln;      // this lane's pair row j
    char* tile = smem + 1024 + w*2048;     // wave-private transpose tile

    // ---- stage pa rows for this block's 8 i's (pair_b0 folded)
    if (t < 64)
        ((f32x4*)pas)[t] = ((const f32x4*)(pa + ((size_t)bnb*PP + ic*8)*HH))[t];

    // ---- Layer-1 W1^T A-fragments (16x16x32: k=8h+{0..7})
    f16x8 wfr1[2];   // [mt]
#pragma unroll
    for (int mt=0; mt<2; mt++){
        f16x8 a;
#pragma unroll
        for (int e=0; e<8; e++)
            a[e] = (_Float16)pw1[(8*h+e)*32 + 16*mt + ln];   // W1^T[m][k]=W1[k][m]
        wfr1[mt] = a;
    }
    // ---- Layer-2 W2^T A-fragments (16x16x16: k=4h+{0..3}, chained kc)
    f16x4 w2t[2][2]; // [mtO][kc]
#pragma unroll
    for (int mtO=0; mtO<2; mtO++)
#pragma unroll
    for (int kc=0; kc<2; kc++){
        f16x4 a;
#pragma unroll
        for (int e=0; e<4; e++)
            a[e] = (_Float16)pw2[(16*kc + 4*h + e)*32 + 16*mtO + ln];
        w2t[mtO][kc] = a;
    }

    // ---- biases as D-fragment f32x4 (feature = 16mt+4h+q)
    f32x4 b1v[2], b2v[2];
#pragma unroll
    for (int mt=0; mt<2; mt++){
        b1v[mt] = *(const f32x4*)(pb1 + 16*mt + 4*h);
        b2v[mt] = *(const f32x4*)(pb2 + 16*mt + 4*h);
    }

    // ---- pb slice: this lane's B-frag k-slice for its single j
    float pbr[8];
    {
        const float* q = pb + ((size_t)bnb*PP + jme)*HH + 8*h;
        f32x4 v0 = *(const f32x4*)q, v1 = *(const f32x4*)(q+4);
#pragma unroll
        for (int c=0;c<4;c++){ pbr[c]=v0[c]; pbr[4+c]=v1[c]; }
    }
    __syncthreads();   // pas visible to all

    for (int i = 0; i < 8; i++){
        // ---- H0^T B-fragment straight into registers (fp16, packed cvt)
        float par[8];
        {
            const f32x4* pp = (const f32x4*)(pas + i*32 + 8*h);
            f32x4 v0 = pp[0], v1 = pp[1];
#pragma unroll
            for (int c=0;c<4;c++){ par[c]=v0[c]; par[4+c]=v1[c]; }
        }
        float e0[8];
#pragma unroll
        for (int e=0; e<8; e++) e0[e] = elu_f(par[e] + pbr[e]);
        f16x2 p0 = pk16(e0[0], e0[1]);
        f16x2 p1 = pk16(e0[2], e0[3]);
        f16x2 p2 = pk16(e0[4], e0[5]);
        f16x2 p3 = pk16(e0[6], e0[7]);
        f16x8 bh = {p0[0],p0[1],p1[0],p1[1],p2[0],p2[1],p3[0],p3[1]};

        // ---- Layer 1: H1^T = W1^T @ H0^T (K=32)
        f32x4 acc[2];   // [mt]
#pragma unroll
        for (int mt=0; mt<2; mt++)
            acc[mt] = __builtin_amdgcn_mfma_f32_16x16x32_f16(
                          wfr1[mt], bh, b1v[mt], 0,0,0);

        // ---- elu + cvt: acc IS the 16x16x16 B-fragment (kc = mt)
        f16x4 bf[2];    // [kc]
#pragma unroll
        for (int kc=0; kc<2; kc++){
            f16x2 q0 = pk16(elu_f(acc[kc][0]), elu_f(acc[kc][1]));
            f16x2 q1 = pk16(elu_f(acc[kc][2]), elu_f(acc[kc][3]));
            f16x4 pp = {q0[0],q0[1],q1[0],q1[1]};
            bf[kc] = pp;
        }

        // ---- Layer 2: O^T = W2^T @ H1^T -> wave-local LDS tile (swizzled)
#pragma unroll
        for (int mtO=0; mtO<2; mtO++){
            f32x4 c = b2v[mtO];
            c = __builtin_amdgcn_mfma_f32_16x16x16f16(w2t[mtO][0], bf[0], c, 0,0,0);
            c = __builtin_amdgcn_mfma_f32_16x16x16f16(w2t[mtO][1], bf[1], c, 0,0,0);
            f32x4 o;
#pragma unroll
            for (int q=0; q<4; q++) o[q] = elu_f(c[q]);
            int slot = (4*mtO + h) ^ (ln & 7);
            *(f32x4*)(tile + ln*128 + slot*16) = o;
        }
        // wave-local RAW: lgkmcnt orders this wave's LDS writes before reads.

        // ---- contiguous NT writeout: 2 x 1 KB full-line streams per wave
        {
            float* gbase = out + ((size_t)(bnb*PP + ic*8 + i))*PP*OUTC
                               + (size_t)(64*p + 16*w)*OUTC;
#pragma unroll
            for (int r=0; r<2; r++){
                int L = l + 64*r;                 // 0..127 = 16 rows x 8 slots
                int j = L >> 3, s = (L & 7) ^ (j & 7);
                f32x4 v = *(const f32x4*)(tile + j*128 + s*16);
                __builtin_nontemporal_store(v, (f32x4*)(gbase + 4*L));
            }
        }
    }
}

extern "C" void kernel_launch(void* const* d_in, const int* in_sizes, int n_in,
                              void* d_out, int out_size, void* d_ws, size_t ws_size,
                              hipStream_t stream) {
    const float* x    = (const float*)d_in[0];
    const float* msk  = (const float*)d_in[1];
    const float* nw0  = (const float*)d_in[2];
    const float* nb0  = (const float*)d_in[3];
    const float* nw1  = (const float*)d_in[4];
    const float* nb1  = (const float*)d_in[5];
    const float* nw2  = (const float*)d_in[6];
    const float* nb2  = (const float*)d_in[7];
    const float* pw0  = (const float*)d_in[8];
    const float* pb0  = (const float*)d_in[9];
    const float* pw1  = (const float*)d_in[10];
    const float* pb1  = (const float*)d_in[11];
    const float* pw2  = (const float*)d_in[12];
    const float* pb2  = (const float*)d_in[13];
    float* out = (float*)d_out;

    float* pa = (float*)d_ws;                       // 8192*32 floats = 1 MiB
    float* pb = pa + (size_t)NROWS*HH;              // +1 MiB

    node_kernel<<<NROWS/256, 256, 0, stream>>>(x, msk, nw0, nb0, nw1, nb1,
                                               nw2, nb2, pw0, pb0, pa, pb);
    pair_kernel<<<BB*NBB*32, 256, 0, stream>>>(pa, pb, pw1, pb1,
                                               pw2, pb2, out);
}

// Round 21
// 50.307 us; speedup vs baseline: 1.3666x; 1.0693x over previous
//
#include <hip/hip_runtime.h>

// Problem dims (fixed by reference)
#define BB   2
#define NBB  32
#define PP   128
#define FF   32
#define HH   32
#define NO   8
#define OUTC 32
#define NROWS (BB*NBB*PP)   // 8192

typedef float    f32x4 __attribute__((ext_vector_type(4)));
typedef _Float16 f16x8 __attribute__((ext_vector_type(8)));
typedef _Float16 f16x4 __attribute__((ext_vector_type(4)));
typedef _Float16 f16x2 __attribute__((ext_vector_type(2)));

__device__ __forceinline__ float elu_f(float x){
    return x > 0.0f ? x : (__expf(x) - 1.0f);
}
// packed fp32x2 -> fp16x2 (RTZ), bit-cast to _Float16 vector type
__device__ __forceinline__ f16x2 pk16(float a, float b){
    return __builtin_bit_cast(f16x2, __builtin_amdgcn_cvt_pkrtz(a, b));
}

// Kernel A: node MLP + projection to pa/pb (pair_b0 folded into pa).
__global__ __launch_bounds__(256) void node_kernel(
    const float* __restrict__ x,  const float* __restrict__ msk,
    const float* __restrict__ w0, const float* __restrict__ b0,
    const float* __restrict__ w1, const float* __restrict__ b1,
    const float* __restrict__ w2, const float* __restrict__ b2,
    const float* __restrict__ pw0,const float* __restrict__ pb0,
    float* __restrict__ pa, float* __restrict__ pb)
{
    int row = blockIdx.x*256 + threadIdx.x;
    if (row >= NROWS) return;

    float xr[FF];
    const float4* xp = reinterpret_cast<const float4*>(x + (size_t)row*FF);
#pragma unroll
    for (int q=0;q<FF/4;q++){ float4 v=xp[q]; xr[4*q]=v.x; xr[4*q+1]=v.y; xr[4*q+2]=v.z; xr[4*q+3]=v.w; }

    float h[HH];
#pragma unroll
    for (int k=0;k<HH;k++) h[k]=b0[k];
#pragma unroll
    for (int m=0;m<FF;m++){
        float xm = xr[m];
#pragma unroll
        for (int k=0;k<HH;k++) h[k] += xm * w0[m*HH+k];
    }
#pragma unroll
    for (int k=0;k<HH;k++) h[k]=elu_f(h[k]);

    float g[HH];
#pragma unroll
    for (int k=0;k<HH;k++) g[k]=b1[k];
#pragma unroll
    for (int m=0;m<HH;m++){
        float hm=h[m];
#pragma unroll
        for (int k=0;k<HH;k++) g[k] += hm * w1[m*HH+k];
    }
#pragma unroll
    for (int k=0;k<HH;k++) g[k]=elu_f(g[k]);

    float mk = msk[row];
    float npj[NO];
#pragma unroll
    for (int k=0;k<NO;k++) npj[k]=b2[k];
#pragma unroll
    for (int m=0;m<HH;m++){
        float gm=g[m];
#pragma unroll
        for (int k=0;k<NO;k++) npj[k] += gm * w2[m*NO+k];
    }
#pragma unroll
    for (int k=0;k<NO;k++) npj[k]=elu_f(npj[k])*mk;

    float pav[HH], pbv[HH];
#pragma unroll
    for (int k=0;k<HH;k++){ pav[k]=pb0[k]; pbv[k]=0.0f; }
#pragma unroll
    for (int m=0;m<NO;m++){
        float nm=npj[m];
#pragma unroll
        for (int k=0;k<HH;k++){
            pav[k] += nm * pw0[m*HH+k];
            pbv[k] += nm * pw0[(NO+m)*HH+k];
        }
    }
    float4* pap = reinterpret_cast<float4*>(pa + (size_t)row*HH);
    float4* pbp = reinterpret_cast<float4*>(pb + (size_t)row*HH);
#pragma unroll
    for (int q=0;q<HH/4;q++){
        pap[q]=make_float4(pav[4*q],pav[4*q+1],pav[4*q+2],pav[4*q+3]);
        pbp[q]=make_float4(pbv[4*q],pbv[4*q+1],pbv[4*q+2],pbv[4*q+3]);
    }
}

// ---- Transposed-MFMA pair kernel, fp16, NT full-line streaming stores ----
// R20 (=R18) = 53.8 us, best known. R20->R21 single change: 4 i's per block
// (grid 2048 -> 4096, 16384 waves). Post-NT regime test: if the residual
// gap (effective drain ~3.3 TB/s vs fill's 6.7) is per-CU outstanding-store
// concurrency, doubling resident wave count raises in-flight NT traffic.
// (This lever nulled pre-NT at R14, but that was under the now-removed L2
// dirty-allocation bottleneck -- regime changed, retest justified.)
// Everything else identical to R20: NT 1 KB full-line writeout via
// wave-local XOR-swizzled LDS tile; zero-LDS layer handoff; jj p-split.
//   A frag (16x16x32): row m=ln(+16mt), k=8h+{0..7}
//   B frag: col=pair j, k=8h+{0..7};  D frag: col=pair j, feat 16mt+4h+{0..3}
#define ICN 4            // i's per block
#define SM_SIZE (ICN*HH*4 + 4*2048)   // pas + 4 wave tiles

__global__ __launch_bounds__(256, 5) void pair_kernel(
    const float* __restrict__ pa, const float* __restrict__ pb,
    const float* __restrict__ pw1, const float* __restrict__ pb1,
    const float* __restrict__ pw2, const float* __restrict__ pb2,
    float* __restrict__ out)
{
    __shared__ __align__(16) char smem[SM_SIZE];
    float* pas = (float*)smem;

    const int t   = threadIdx.x;
    const int l   = t & 63;
    const int w   = t >> 6;
    const int h   = l >> 4;
    const int ln  = l & 15;
    const int bnb = blockIdx.x >> 6;           // 64 blocks per bnb
    const int ic  = (blockIdx.x >> 1) & 31;    // 32 chunks of ICN=4 i's
    const int p   = blockIdx.x & 1;
    const int jme = 64*p + 16*w + ln;      // this lane's pair row j
    char* tile = smem + ICN*HH*4 + w*2048; // wave-private transpose tile

    // ---- stage pa rows for this block's ICN i's (pair_b0 folded)
    if (t < ICN*HH/4)
        ((f32x4*)pas)[t] = ((const f32x4*)(pa + ((size_t)bnb*PP + ic*ICN)*HH))[t];

    // ---- Layer-1 W1^T A-fragments (16x16x32: k=8h+{0..7})
    f16x8 wfr1[2];   // [mt]
#pragma unroll
    for (int mt=0; mt<2; mt++){
        f16x8 a;
#pragma unroll
        for (int e=0; e<8; e++)
            a[e] = (_Float16)pw1[(8*h+e)*32 + 16*mt + ln];   // W1^T[m][k]=W1[k][m]
        wfr1[mt] = a;
    }
    // ---- Layer-2 W2^T A-fragments (16x16x16: k=4h+{0..3}, chained kc)
    f16x4 w2t[2][2]; // [mtO][kc]
#pragma unroll
    for (int mtO=0; mtO<2; mtO++)
#pragma unroll
    for (int kc=0; kc<2; kc++){
        f16x4 a;
#pragma unroll
        for (int e=0; e<4; e++)
            a[e] = (_Float16)pw2[(16*kc + 4*h + e)*32 + 16*mtO + ln];
        w2t[mtO][kc] = a;
    }

    // ---- biases as D-fragment f32x4 (feature = 16mt+4h+q)
    f32x4 b1v[2], b2v[2];
#pragma unroll
    for (int mt=0; mt<2; mt++){
        b1v[mt] = *(const f32x4*)(pb1 + 16*mt + 4*h);
        b2v[mt] = *(const f32x4*)(pb2 + 16*mt + 4*h);
    }

    // ---- pb slice: this lane's B-frag k-slice for its single j
    float pbr[8];
    {
        const float* q = pb + ((size_t)bnb*PP + jme)*HH + 8*h;
        f32x4 v0 = *(const f32x4*)q, v1 = *(const f32x4*)(q+4);
#pragma unroll
        for (int c=0;c<4;c++){ pbr[c]=v0[c]; pbr[4+c]=v1[c]; }
    }
    __syncthreads();   // pas visible to all

    for (int i = 0; i < ICN; i++){
        // ---- H0^T B-fragment straight into registers (fp16, packed cvt)
        float par[8];
        {
            const f32x4* pp = (const f32x4*)(pas + i*32 + 8*h);
            f32x4 v0 = pp[0], v1 = pp[1];
#pragma unroll
            for (int c=0;c<4;c++){ par[c]=v0[c]; par[4+c]=v1[c]; }
        }
        float e0[8];
#pragma unroll
        for (int e=0; e<8; e++) e0[e] = elu_f(par[e] + pbr[e]);
        f16x2 p0 = pk16(e0[0], e0[1]);
        f16x2 p1 = pk16(e0[2], e0[3]);
        f16x2 p2 = pk16(e0[4], e0[5]);
        f16x2 p3 = pk16(e0[6], e0[7]);
        f16x8 bh = {p0[0],p0[1],p1[0],p1[1],p2[0],p2[1],p3[0],p3[1]};

        // ---- Layer 1: H1^T = W1^T @ H0^T (K=32)
        f32x4 acc[2];   // [mt]
#pragma unroll
        for (int mt=0; mt<2; mt++)
            acc[mt] = __builtin_amdgcn_mfma_f32_16x16x32_f16(
                          wfr1[mt], bh, b1v[mt], 0,0,0);

        // ---- elu + cvt: acc IS the 16x16x16 B-fragment (kc = mt)
        f16x4 bf[2];    // [kc]
#pragma unroll
        for (int kc=0; kc<2; kc++){
            f16x2 q0 = pk16(elu_f(acc[kc][0]), elu_f(acc[kc][1]));
            f16x2 q1 = pk16(elu_f(acc[kc][2]), elu_f(acc[kc][3]));
            f16x4 pp = {q0[0],q0[1],q1[0],q1[1]};
            bf[kc] = pp;
        }

        // ---- Layer 2: O^T = W2^T @ H1^T -> wave-local LDS tile (swizzled)
#pragma unroll
        for (int mtO=0; mtO<2; mtO++){
            f32x4 c = b2v[mtO];
            c = __builtin_amdgcn_mfma_f32_16x16x16f16(w2t[mtO][0], bf[0], c, 0,0,0);
            c = __builtin_amdgcn_mfma_f32_16x16x16f16(w2t[mtO][1], bf[1], c, 0,0,0);
            f32x4 o;
#pragma unroll
            for (int q=0; q<4; q++) o[q] = elu_f(c[q]);
            int slot = (4*mtO + h) ^ (ln & 7);
            *(f32x4*)(tile + ln*128 + slot*16) = o;
        }
        // wave-local RAW: lgkmcnt orders this wave's LDS writes before reads.

        // ---- contiguous NT writeout: 2 x 1 KB full-line streams per wave
        {
            float* gbase = out + ((size_t)(bnb*PP + ic*ICN + i))*PP*OUTC
                               + (size_t)(64*p + 16*w)*OUTC;
#pragma unroll
            for (int r=0; r<2; r++){
                int L = l + 64*r;                 // 0..127 = 16 rows x 8 slots
                int j = L >> 3, s = (L & 7) ^ (j & 7);
                f32x4 v = *(const f32x4*)(tile + j*128 + s*16);
                __builtin_nontemporal_store(v, (f32x4*)(gbase + 4*L));
            }
        }
    }
}

extern "C" void kernel_launch(void* const* d_in, const int* in_sizes, int n_in,
                              void* d_out, int out_size, void* d_ws, size_t ws_size,
                              hipStream_t stream) {
    const float* x    = (const float*)d_in[0];
    const float* msk  = (const float*)d_in[1];
    const float* nw0  = (const float*)d_in[2];
    const float* nb0  = (const float*)d_in[3];
    const float* nw1  = (const float*)d_in[4];
    const float* nb1  = (const float*)d_in[5];
    const float* nw2  = (const float*)d_in[6];
    const float* nb2  = (const float*)d_in[7];
    const float* pw0  = (const float*)d_in[8];
    const float* pb0  = (const float*)d_in[9];
    const float* pw1  = (const float*)d_in[10];
    const float* pb1  = (const float*)d_in[11];
    const float* pw2  = (const float*)d_in[12];
    const float* pb2  = (const float*)d_in[13];
    float* out = (float*)d_out;

    float* pa = (float*)d_ws;                       // 8192*32 floats = 1 MiB
    float* pb = pa + (size_t)NROWS*HH;              // +1 MiB

    node_kernel<<<NROWS/256, 256, 0, stream>>>(x, msk, nw0, nb0, nw1, nb1,
                                               nw2, nb2, pw0, pb0, pa, pb);
    pair_kernel<<<BB*NBB*64, 256, 0, stream>>>(pa, pb, pw1, pb1,
                                               pw2, pb2, out);
}